// Round 23
// baseline (608.472 us; speedup 1.0000x reference)
//
#include <hip/hip_runtime.h>

// Problem constants (from reference): B=256, T=2048, I=12, H=64
constexpr int Bn = 256;
constexpr int Tn = 2048;
constexpr int In = 12;
constexpr int Hn = 64;
constexpr int TCH = 512;     // steps per staged x quarter (padded to 16)
constexpr int CHUNK = 32;    // fc-flush granularity == hist ring depth

constexpr float LOG2E = 1.44269504088896340736f;

typedef float v2f __attribute__((ext_vector_type(2)));

__device__ __forceinline__ float frcp(float v) { return __builtin_amdgcn_rcpf(v); }

// quad_perm DPP: cross-lane move within each group of 4 lanes, pure VALU.
template <int CTRL>
__device__ __forceinline__ float dppq(float v) {
    int i = __float_as_int(v);
    i = __builtin_amdgcn_mov_dpp(i, CTRL, 0xF, 0xF, false);
    return __int_as_float(i);
}

// Round-23 = r22 (quad-K-split + treduce + packed FMA + x-pipeline, 1
// barrier/step; 592us) minus residual overhead:
//  - hist ring IS the recurrence buffer (read hist[s-1], write hist[s];
//    cross-chunk wrap to the other parity) -> one ds_write/step deleted.
//  - CHUNK 32: half the flush lumps; flush does 32 outputs, 8 h/thread.
//  - biasv pre-packed as v2f -> kills 4 v_mov/step in XPROJ.
extern "C" __global__ void __launch_bounds__(256, 1)
lstm_fused_kernel(const float* __restrict__ x,
                  const float* __restrict__ w_ih,
                  const float* __restrict__ w_hh,
                  const float* __restrict__ b_ih,
                  const float* __restrict__ b_hh,
                  const float* __restrict__ fc_w,
                  const float* __restrict__ fc_b,
                  float* __restrict__ out)
{
    __shared__ __align__(16) float xbuf[TCH * 16];        // 32 KiB (x quarter)
    __shared__ __align__(16) float hist[2][CHUNK * Hn];   // 16 KiB h ring + fc

    const int tid  = threadIdx.x;       // 0..255
    const int lane = tid & 63;
    const int w    = tid >> 6;          // wave id 0..3
    const int ks   = lane & 3;          // K-slice id == owned gate id
    const int j4   = lane >> 2;         // 0..15
    const int j    = 16 * w + j4;       // owned h index
    const int b    = blockIdx.x;

    const float4* xsrc4 = (const float4*)(x + (size_t)b * Tn * In);

    // ---- zero the x padding columns (i = 12..15) once ----
    #pragma unroll
    for (int k = 0; k < 8; ++k) {
        int idx = tid + k * 256;                       // 0..2047
        xbuf[(idx >> 2) * 16 + 12 + (idx & 3)] = 0.0f;
    }

    // ---- per-lane weights as float2 pairs (v_pk_fma operands) ----
    v2f whh_p[4][8];
    #pragma unroll
    for (int m = 0; m < 4; ++m) {
        const float4* src = (const float4*)(w_hh + (64 * m + j) * Hn + 16 * ks);
        float4 v0 = src[0], v1 = src[1], v2 = src[2], v3 = src[3];
        whh_p[m][0] = v2f{v0.x, v0.y};  whh_p[m][1] = v2f{v0.z, v0.w};
        whh_p[m][2] = v2f{v1.x, v1.y};  whh_p[m][3] = v2f{v1.z, v1.w};
        whh_p[m][4] = v2f{v2.x, v2.y};  whh_p[m][5] = v2f{v2.z, v2.w};
        whh_p[m][6] = v2f{v3.x, v3.y};  whh_p[m][7] = v2f{v3.z, v3.w};
    }
    #pragma unroll
    for (int m = 0; m < 4; ++m)
        #pragma unroll
        for (int t = 0; t < 8; ++t)
            asm volatile("" : "+v"(whh_p[m][t]));

    v2f wih_p[4][2];
    if (ks < 3) {
        #pragma unroll
        for (int m = 0; m < 4; ++m) {
            float4 v = *(const float4*)(w_ih + (64 * m + j) * In + 4 * ks);
            wih_p[m][0] = v2f{v.x, v.y};
            wih_p[m][1] = v2f{v.z, v.w};
        }
    } else {
        #pragma unroll
        for (int m = 0; m < 4; ++m) {
            wih_p[m][0] = v2f{0.f, 0.f};
            wih_p[m][1] = v2f{0.f, 0.f};
        }
    }
    #pragma unroll
    for (int m = 0; m < 4; ++m) {
        asm volatile("" : "+v"(wih_p[m][0]));
        asm volatile("" : "+v"(wih_p[m][1]));
    }

    // bias folded into ks==0 lane's accumulator init (summed by treduce),
    // pre-packed as v2f so XPROJ needs no mov.
    v2f biasv[4];
    #pragma unroll
    for (int m = 0; m < 4; ++m)
        biasv[m] = v2f{(ks == 0) ? (b_ih[64 * m + j] + b_hh[64 * m + j]) : 0.0f,
                       0.0f};

    // own-gate activation constants (gate id == ks; gate 2 is tanh)
    const float scl  = (ks == 2) ? 2.0f : 1.0f;
    const float soff = (ks == 2) ? -1.0f : 0.0f;
    const float me   = (ks == 2) ? (-2.0f * LOG2E) : (-LOG2E);

    // fc flush constants: thread (fs, fe) covers h[8fe..8fe+8) of step fs
    const int   fs  = tid >> 3;          // 0..31
    const int   fe  = tid & 7;           // 0..7
    const float4 fwa = *(const float4*)(fc_w + 8 * fe);
    const float4 fwb = *(const float4*)(fc_w + 8 * fe + 4);
    const float fcb = fc_b[0];

    float c = 0.0f;                      // cell state for j (quad-redundant)
    if (tid < Hn) hist[1][(CHUNK - 1) * Hn + tid] = 0.0f;  // h_{-1} = 0

    float* outb = out + (size_t)b * Tn;

    v2f xa0, xa1, xa2, xa3;              // pipelined x+bias acc (packed)

    // packed x-projection for local step TL -> xa0..3
    #define XPROJ(TL) {                                                      \
        const float4 xv = *(const float4*)(xbuf + (TL) * 16 + 4 * ks);       \
        v2f xp0 = v2f{xv.x, xv.y}, xp1 = v2f{xv.z, xv.w};                    \
        xa0 = __builtin_elementwise_fma(xp0, wih_p[0][0], biasv[0]);         \
        xa1 = __builtin_elementwise_fma(xp0, wih_p[1][0], biasv[1]);         \
        xa2 = __builtin_elementwise_fma(xp0, wih_p[2][0], biasv[2]);         \
        xa3 = __builtin_elementwise_fma(xp0, wih_p[3][0], biasv[3]);         \
        xa0 = __builtin_elementwise_fma(xp1, wih_p[0][1], xa0);              \
        xa1 = __builtin_elementwise_fma(xp1, wih_p[1][1], xa1);              \
        xa2 = __builtin_elementwise_fma(xp1, wih_p[2][1], xa2);              \
        xa3 = __builtin_elementwise_fma(xp1, wih_p[3][1], xa3); }

    for (int ci = 0; ci < Tn / CHUNK; ++ci) {
        const int T0  = ci * CHUNK;
        const int par = ci & 1;

        // ---- stage x quarter; recompute xa for step T0 ----
        if ((T0 & (TCH - 1)) == 0) {
            const int qtr = T0 >> 9;
            #pragma unroll
            for (int k = 0; k < 6; ++k) {
                int li  = tid + k * 256;              // 0..1535 (float4s)
                int t_l = li / 3;
                int i4  = li % 3;
                ((float4*)xbuf)[t_l * 4 + i4] = xsrc4[qtr * 1536 + li];
            }
            __syncthreads();
            XPROJ(T0 & (TCH - 1))
        }

        float*       histC = hist[par];
        const float* histP = hist[par ^ 1];

        #pragma unroll
        for (int s = 0; s < CHUNK; ++s) {
            const float* hprev = (s == 0) ? (histP + (CHUNK - 1) * Hn)
                                          : (histC + (s - 1) * Hn);

            // ---- h K-slice read (uniform per quad-group; 2-way = free) ----
            const float4* hp = (const float4*)hprev + 4 * ks;
            float4 h0 = hp[0], h1 = hp[1], h2 = hp[2], h3 = hp[3];
            v2f hq0 = v2f{h0.x, h0.y}, hq1 = v2f{h0.z, h0.w};
            v2f hq2 = v2f{h1.x, h1.y}, hq3 = v2f{h1.z, h1.w};
            v2f hq4 = v2f{h2.x, h2.y}, hq5 = v2f{h2.z, h2.w};
            v2f hq6 = v2f{h3.x, h3.y}, hq7 = v2f{h3.z, h3.w};

            v2f a0 = xa0, a1 = xa1, a2 = xa2, a3 = xa3;
            #define HF(HQ, T) \
                a0 = __builtin_elementwise_fma(HQ, whh_p[0][T], a0); \
                a1 = __builtin_elementwise_fma(HQ, whh_p[1][T], a1); \
                a2 = __builtin_elementwise_fma(HQ, whh_p[2][T], a2); \
                a3 = __builtin_elementwise_fma(HQ, whh_p[3][T], a3);
            HF(hq0, 0) HF(hq1, 1) HF(hq2, 2) HF(hq3, 3)
            HF(hq4, 4) HF(hq5, 5) HF(hq6, 6) HF(hq7, 7)
            #undef HF

            float s0  = a0.x + a0.y;
            float s1  = a1.x + a1.y;
            float s2m = a2.x + a2.y;
            float s3  = a3.x + a3.y;

            // ---- transpose-reduce: gate ks's TOTAL lands in quad lane ks ----
            float p  = (ks & 1) ? s1 : s0;
            float q  = (ks & 1) ? s0 : s1;
            p += dppq<0xB1>(q);
            float r2 = (ks & 1) ? s3 : s2m;
            float t2 = (ks & 1) ? s2m : s3;
            r2 += dppq<0xB1>(t2);
            float v  = (ks & 2) ? r2 : p;
            float u  = (ks & 2) ? p : r2;
            v += dppq<0x4E>(u);

            // ---- pipeline: packed x-projection for step s+1 ----
            {
                const int tln = (T0 + s + 1) & (TCH - 1);
                XPROJ(tln)
            }

            // ---- ONE activation per lane (own gate), then quad broadcast ----
            float e   = exp2f(me * v);
            float act = fmaf(scl, frcp(1.0f + e), soff);

            float iv = dppq<0x00>(act);
            float fv = dppq<0x55>(act);
            float gv = dppq<0xAA>(act);
            float ov = dppq<0xFF>(act);

            c = fmaf(fv, c, iv * gv);
            float ec = exp2f(-2.0f * LOG2E * c);
            float h  = ov * fmaf(2.0f, frcp(1.0f + ec), -1.0f);

            if (ks == 0) histC[s * Hn + j] = h;    // ring publish (also fc)
            __syncthreads();             // the ONE barrier per step
        }

        // ---- fc flush: histC complete as of the last step barrier ----
        // No extra barrier: next chunk writes hist[par^1]; histC is
        // rewritten only after >=33 further barriers.
        {
            const float* hr = histC + fs * Hn + 8 * fe;
            const float4 hv0 = *(const float4*)(hr);
            const float4 hv1 = *(const float4*)(hr + 4);
            float pp = hv0.x * fwa.x + hv0.y * fwa.y + hv0.z * fwa.z + hv0.w * fwa.w
                     + hv1.x * fwb.x + hv1.y * fwb.y + hv1.z * fwb.z + hv1.w * fwb.w;
            pp += __shfl_xor(pp, 1, 8);
            pp += __shfl_xor(pp, 2, 8);
            pp += __shfl_xor(pp, 4, 8);
            if (fe == 0) outb[T0 + fs] = pp + fcb;
        }
    }
    #undef XPROJ
}

extern "C" void kernel_launch(void* const* d_in, const int* in_sizes, int n_in,
                              void* d_out, int out_size, void* d_ws, size_t ws_size,
                              hipStream_t stream) {
    const float* x    = (const float*)d_in[0];
    const float* w_ih = (const float*)d_in[1];
    const float* w_hh = (const float*)d_in[2];
    const float* b_ih = (const float*)d_in[3];
    const float* b_hh = (const float*)d_in[4];
    const float* fc_w = (const float*)d_in[5];
    const float* fc_b = (const float*)d_in[6];
    float* out = (float*)d_out;

    lstm_fused_kernel<<<Bn, 256, 0, stream>>>(x, w_ih, w_hh, b_ih, b_hh,
                                              fc_w, fc_b, out);
}

// Round 24
// 590.919 us; speedup vs baseline: 1.0297x; 1.0297x over previous
//
#include <hip/hip_runtime.h>

// Problem constants (from reference): B=256, T=2048, I=12, H=64
constexpr int Bn = 256;
constexpr int Tn = 2048;
constexpr int In = 12;
constexpr int Hn = 64;
constexpr int TCH = 512;     // steps per staged x quarter (padded to 16)
constexpr int CHUNK = 16;    // fc-flush granularity == hist depth

constexpr float LOG2E = 1.44269504088896340736f;

typedef float v2f __attribute__((ext_vector_type(2)));

__device__ __forceinline__ float frcp(float v) { return __builtin_amdgcn_rcpf(v); }

// quad_perm DPP: cross-lane move within each group of 4 lanes, pure VALU.
template <int CTRL>
__device__ __forceinline__ float dppq(float v) {
    int i = __float_as_int(v);
    i = __builtin_amdgcn_mov_dpp(i, CTRL, 0xF, 0xF, false);
    return __int_as_float(i);
}

// Round-24 = exact revert to round-22 (592 us, the measured optimum).
// r23's bundle (ring recurrence + CHUNK32 + biasv) regressed +2.7%:
// CHUNK32's flush reads (8fe stride, fs*64 = 0 mod 32) are 8-way bank
// conflicted, and the step-variant ring pointers added per-step address
// work. Structure: quad-K-split + transpose-reduce + packed v_pk_fma_f32
// dots + pipelined x-projection, ONE barrier per step.
extern "C" __global__ void __launch_bounds__(256, 1)
lstm_fused_kernel(const float* __restrict__ x,
                  const float* __restrict__ w_ih,
                  const float* __restrict__ w_hh,
                  const float* __restrict__ b_ih,
                  const float* __restrict__ b_hh,
                  const float* __restrict__ fc_w,
                  const float* __restrict__ fc_b,
                  float* __restrict__ out)
{
    __shared__ __align__(16) float xbuf[TCH * 16];        // 32 KiB (x quarter)
    __shared__ __align__(16) float hbuf[2][Hn];           // ping-pong h
    __shared__ __align__(16) float hist[2][CHUNK][Hn];    // 8 KiB fc history

    const int tid  = threadIdx.x;       // 0..255
    const int lane = tid & 63;
    const int w    = tid >> 6;          // wave id 0..3
    const int ks   = lane & 3;          // K-slice id == owned gate id
    const int j4   = lane >> 2;         // 0..15
    const int j    = 16 * w + j4;       // owned h index
    const int b    = blockIdx.x;

    const float4* xsrc4 = (const float4*)(x + (size_t)b * Tn * In);

    // ---- zero the x padding columns (i = 12..15) once ----
    #pragma unroll
    for (int k = 0; k < 8; ++k) {
        int idx = tid + k * 256;                       // 0..2047
        xbuf[(idx >> 2) * 16 + 12 + (idx & 3)] = 0.0f;
    }

    // ---- per-lane weights as float2 pairs (v_pk_fma operands) ----
    v2f whh_p[4][8];
    #pragma unroll
    for (int m = 0; m < 4; ++m) {
        const float4* src = (const float4*)(w_hh + (64 * m + j) * Hn + 16 * ks);
        float4 v0 = src[0], v1 = src[1], v2 = src[2], v3 = src[3];
        whh_p[m][0] = v2f{v0.x, v0.y};  whh_p[m][1] = v2f{v0.z, v0.w};
        whh_p[m][2] = v2f{v1.x, v1.y};  whh_p[m][3] = v2f{v1.z, v1.w};
        whh_p[m][4] = v2f{v2.x, v2.y};  whh_p[m][5] = v2f{v2.z, v2.w};
        whh_p[m][6] = v2f{v3.x, v3.y};  whh_p[m][7] = v2f{v3.z, v3.w};
    }
    #pragma unroll
    for (int m = 0; m < 4; ++m)
        #pragma unroll
        for (int t = 0; t < 8; ++t)
            asm volatile("" : "+v"(whh_p[m][t]));

    v2f wih_p[4][2];
    if (ks < 3) {
        #pragma unroll
        for (int m = 0; m < 4; ++m) {
            float4 v = *(const float4*)(w_ih + (64 * m + j) * In + 4 * ks);
            wih_p[m][0] = v2f{v.x, v.y};
            wih_p[m][1] = v2f{v.z, v.w};
        }
    } else {
        #pragma unroll
        for (int m = 0; m < 4; ++m) {
            wih_p[m][0] = v2f{0.f, 0.f};
            wih_p[m][1] = v2f{0.f, 0.f};
        }
    }
    #pragma unroll
    for (int m = 0; m < 4; ++m) {
        asm volatile("" : "+v"(wih_p[m][0]));
        asm volatile("" : "+v"(wih_p[m][1]));
    }

    // bias folded into ks==0 lane's accumulator init (summed by treduce)
    float bias[4];
    #pragma unroll
    for (int m = 0; m < 4; ++m)
        bias[m] = (ks == 0) ? (b_ih[64 * m + j] + b_hh[64 * m + j]) : 0.0f;

    // own-gate activation constants (gate id == ks; gate 2 is tanh)
    const float scl  = (ks == 2) ? 2.0f : 1.0f;
    const float soff = (ks == 2) ? -1.0f : 0.0f;
    const float me   = (ks == 2) ? (-2.0f * LOG2E) : (-LOG2E);

    // fc flush constants
    const int   fq  = tid & 15;
    const int   fs  = tid >> 4;          // 0..15
    const float4 fw4 = *(const float4*)(fc_w + 4 * fq);
    const float fcb = fc_b[0];

    float c = 0.0f;                      // cell state for j (quad-redundant)
    if (tid < Hn) hbuf[1][tid] = 0.0f;   // h_{-1} = 0 (step 0 reads hbuf[1])

    float* outb = out + (size_t)b * Tn;

    v2f xa0, xa1, xa2, xa3;              // pipelined x+bias acc (packed)

    // packed x-projection for local step TL -> xa0..3
    #define XPROJ(TL) {                                                      \
        const float4 xv = *(const float4*)(xbuf + (TL) * 16 + 4 * ks);       \
        v2f xp0 = v2f{xv.x, xv.y}, xp1 = v2f{xv.z, xv.w};                    \
        xa0 = __builtin_elementwise_fma(xp0, wih_p[0][0], v2f{bias[0], 0.f});\
        xa1 = __builtin_elementwise_fma(xp0, wih_p[1][0], v2f{bias[1], 0.f});\
        xa2 = __builtin_elementwise_fma(xp0, wih_p[2][0], v2f{bias[2], 0.f});\
        xa3 = __builtin_elementwise_fma(xp0, wih_p[3][0], v2f{bias[3], 0.f});\
        xa0 = __builtin_elementwise_fma(xp1, wih_p[0][1], xa0);              \
        xa1 = __builtin_elementwise_fma(xp1, wih_p[1][1], xa1);              \
        xa2 = __builtin_elementwise_fma(xp1, wih_p[2][1], xa2);              \
        xa3 = __builtin_elementwise_fma(xp1, wih_p[3][1], xa3); }

    for (int ci = 0; ci < Tn / CHUNK; ++ci) {
        const int T0  = ci * CHUNK;
        const int par = ci & 1;

        // ---- stage x quarter; recompute xa for step T0 ----
        if ((T0 & (TCH - 1)) == 0) {
            const int qtr = T0 >> 9;
            #pragma unroll
            for (int k = 0; k < 6; ++k) {
                int li  = tid + k * 256;              // 0..1535 (float4s)
                int t_l = li / 3;
                int i4  = li % 3;
                ((float4*)xbuf)[t_l * 4 + i4] = xsrc4[qtr * 1536 + li];
            }
            __syncthreads();
            XPROJ(0)
        }

        #pragma unroll
        for (int s = 0; s < CHUNK; ++s) {
            // ---- h K-slice read (uniform per 16-lane group; 2-way = free) ----
            const float4* hp = (const float4*)hbuf[(s & 1) ^ 1] + 4 * ks;
            float4 h0 = hp[0], h1 = hp[1], h2 = hp[2], h3 = hp[3];
            v2f hq0 = v2f{h0.x, h0.y}, hq1 = v2f{h0.z, h0.w};
            v2f hq2 = v2f{h1.x, h1.y}, hq3 = v2f{h1.z, h1.w};
            v2f hq4 = v2f{h2.x, h2.y}, hq5 = v2f{h2.z, h2.w};
            v2f hq6 = v2f{h3.x, h3.y}, hq7 = v2f{h3.z, h3.w};

            v2f a0 = xa0, a1 = xa1, a2 = xa2, a3 = xa3;
            #define HF(HQ, T) \
                a0 = __builtin_elementwise_fma(HQ, whh_p[0][T], a0); \
                a1 = __builtin_elementwise_fma(HQ, whh_p[1][T], a1); \
                a2 = __builtin_elementwise_fma(HQ, whh_p[2][T], a2); \
                a3 = __builtin_elementwise_fma(HQ, whh_p[3][T], a3);
            HF(hq0, 0) HF(hq1, 1) HF(hq2, 2) HF(hq3, 3)
            HF(hq4, 4) HF(hq5, 5) HF(hq6, 6) HF(hq7, 7)
            #undef HF

            float s0 = a0.x + a0.y;
            float s1 = a1.x + a1.y;
            float s2m = a2.x + a2.y;
            float s3 = a3.x + a3.y;

            // ---- transpose-reduce: gate ks's TOTAL lands in quad lane ks ----
            float p  = (ks & 1) ? s1 : s0;
            float q  = (ks & 1) ? s0 : s1;
            p += dppq<0xB1>(q);
            float r2 = (ks & 1) ? s3 : s2m;
            float t2 = (ks & 1) ? s2m : s3;
            r2 += dppq<0xB1>(t2);
            float v  = (ks & 2) ? r2 : p;
            float u  = (ks & 2) ? p : r2;
            v += dppq<0x4E>(u);

            // ---- pipeline: packed x-projection for step s+1 ----
            {
                const int tln = (T0 + s + 1) & (TCH - 1);
                XPROJ(tln)
            }

            // ---- ONE activation per lane (own gate), then quad broadcast ----
            float e   = exp2f(me * v);
            float act = fmaf(scl, frcp(1.0f + e), soff);

            float iv = dppq<0x00>(act);
            float fv = dppq<0x55>(act);
            float gv = dppq<0xAA>(act);
            float ov = dppq<0xFF>(act);

            c = fmaf(fv, c, iv * gv);
            float ec = exp2f(-2.0f * LOG2E * c);
            float h  = ov * fmaf(2.0f, frcp(1.0f + ec), -1.0f);

            if (ks == 0) {
                hbuf[s & 1][j]  = h;     // recurrence publish
                hist[par][s][j] = h;     // fc history
            }
            __syncthreads();             // the ONE barrier per step
        }

        // ---- fc flush: hist[par] complete as of the last step barrier ----
        // No extra barrier: next chunk writes hist[par^1]; hist[par] is
        // rewritten only after >=17 further barriers.
        {
            const float4 hv = *(const float4*)(&hist[par][fs][4 * fq]);
            float pp = hv.x * fw4.x + hv.y * fw4.y + hv.z * fw4.z + hv.w * fw4.w;
            #pragma unroll
            for (int off = 8; off; off >>= 1)
                pp += __shfl_xor(pp, off, 16);
            if (fq == 0) outb[T0 + fs] = pp + fcb;
        }
    }
    #undef XPROJ
}

extern "C" void kernel_launch(void* const* d_in, const int* in_sizes, int n_in,
                              void* d_out, int out_size, void* d_ws, size_t ws_size,
                              hipStream_t stream) {
    const float* x    = (const float*)d_in[0];
    const float* w_ih = (const float*)d_in[1];
    const float* w_hh = (const float*)d_in[2];
    const float* b_ih = (const float*)d_in[3];
    const float* b_hh = (const float*)d_in[4];
    const float* fc_w = (const float*)d_in[5];
    const float* fc_b = (const float*)d_in[6];
    float* out = (float*)d_out;

    lstm_fused_kernel<<<Bn, 256, 0, stream>>>(x, w_ih, w_hh, b_ih, b_hh,
                                              fc_w, fc_b, out);
}